// Round 4
// 166.253 us; speedup vs baseline: 1.1148x; 1.1148x over previous
//
#include <hip/hip_runtime.h>
#include <math.h>

#define PROJ 8192
#define CDIM 512
#define HWPOS 196
#define NBATCH 32
#define NSLAB 7             // K padded 196 -> 224 = 7 slabs of 32
#define NTP 16              // 4 diag tiles + 6 off-diag pairs x {fwd, mirror} WGs

typedef __attribute__((ext_vector_type(8))) short   short8;
typedef __attribute__((ext_vector_type(4))) float   f32x4;

__device__ __forceinline__ unsigned short f2bf(float f) {
    unsigned u = __float_as_uint(f);
    u += 0x7fff + ((u >> 16) & 1);          // round-to-nearest-even
    return (unsigned short)(u >> 16);
}
__device__ __forceinline__ float bf2f(unsigned short h) {
    return __uint_as_float(((unsigned)h) << 16);
}

// Native no-return LDS fp32 atomic add. unsafeAtomicAdd/atomicAdd on a
// generic pointer into LDS takes the safe CAS path (~400 cyc/op); ds_add_f32
// is single-issue. lgkmcnt drained by __syncthreads().
__device__ __forceinline__ void lds_fadd(float* p, float v) {
    __attribute__((address_space(3))) float* lp =
        (__attribute__((address_space(3))) float*)p;
    asm volatile("ds_add_f32 %0, %1" : : "v"(lp), "v"(v) : "memory");
}

// ---------------------------------------------------------------------------
// Kernel 1: extract (h, s) from the dense sketch matrices + zero norm accum.
// (verbatim round-0)
// ---------------------------------------------------------------------------
__global__ __launch_bounds__(256) void extract_kernel(
    const float* __restrict__ M1, const float* __restrict__ M2,
    int* __restrict__ h1, float* __restrict__ s1,
    int* __restrict__ h2, float* __restrict__ s2,
    float* __restrict__ norm)
{
    const int row = blockIdx.x;
    const float* M = blockIdx.y ? M2 : M1;
    int*   h = blockIdx.y ? h2 : h1;
    float* s = blockIdx.y ? s2 : s1;
    const float* mrow = M + (size_t)row * PROJ;

    if (blockIdx.x == 0 && blockIdx.y == 0 && threadIdx.x < NBATCH)
        norm[threadIdx.x] = 0.0f;

    for (int i = threadIdx.x * 4; i < PROJ; i += 256 * 4) {
        float4 v = *(const float4*)(mrow + i);
        if (v.x != 0.0f) { h[row] = i + 0; s[row] = v.x; }
        if (v.y != 0.0f) { h[row] = i + 1; s[row] = v.y; }
        if (v.z != 0.0f) { h[row] = i + 2; s[row] = v.z; }
        if (v.w != 0.0f) { h[row] = i + 3; s[row] = v.w; }
    }
}

// ---------------------------------------------------------------------------
// Kernel 2: prep — split fp32 x into bf16 hi/lo, transpose to fragment order.
// Output layout (ushort): [b][kslab(7)][cgrp(32)][quad(4)][c16(16)][j(8)]
// i.e. element (c = cgrp*16+c16, k = kslab*32+quad*8+j); k>=196 zero-padded.
// (verbatim round-0)
// ---------------------------------------------------------------------------
__global__ __launch_bounds__(256) void prep_kernel(
    const float* __restrict__ x,
    unsigned short* __restrict__ XThi, unsigned short* __restrict__ XTlo)
{
    const int ks  = blockIdx.x;
    const int bat = blockIdx.y;
    const int tid = threadIdx.x;
    __shared__ float xt[32][513];            // +1 pad breaks bank conflicts

    const float* xb = x + (size_t)bat * HWPOS * CDIM;
    const int k0 = ks * 32;
#pragma unroll
    for (int i = 0; i < 16; ++i) {
        const int idx = i * 1024 + tid * 4;
        const int kr  = idx >> 9;
        const int c   = idx & 511;
        float4 v = make_float4(0.f, 0.f, 0.f, 0.f);
        if (k0 + kr < HWPOS) v = *(const float4*)(xb + (size_t)(k0 + kr) * CDIM + c);
        xt[kr][c+0] = v.x; xt[kr][c+1] = v.y; xt[kr][c+2] = v.z; xt[kr][c+3] = v.w;
    }
    __syncthreads();

    unsigned short* ohi = XThi + ((size_t)bat * NSLAB + ks) * 16384;
    unsigned short* olo = XTlo + ((size_t)bat * NSLAB + ks) * 16384;
#pragma unroll
    for (int i = 0; i < 8; ++i) {
        const int ch   = i * 256 + tid;      // chunk 0..2047, memory order
        const int c16  = ch & 15;
        const int quad = (ch >> 4) & 3;
        const int cgrp = ch >> 6;
        const int c    = cgrp * 16 + c16;
        short8 vh, vl;
#pragma unroll
        for (int j = 0; j < 8; ++j) {
            float f = xt[quad * 8 + j][c];
            unsigned short h = f2bf(f);
            vh[j] = (short)h;
            vl[j] = (short)f2bf(f - bf2f(h));
        }
        *(short8*)(ohi + ch * 8) = vh;
        *(short8*)(olo + ch * 8) = vl;
    }
}

// ---------------------------------------------------------------------------
// Kernel 3: fused Gram (bf16x2 MFMA) + count-sketch scatter.
// ROUND-0 BODY VERBATIM (double-buffered Sbuf, async global_load_lds,
// identical barrier structure, identical scatter lines). Sole change: the
// 10 tile-pair units become 16 balanced units — 4 diag (fwd-only) + 6
// off-diag pairs each split into a fwd-WG and a mirror-WG that recompute the
// same MFMA tile (MFMA was 3% util; duplication is free). 512 WGs = 2 clean
// dispatch rounds of 256 CUs, every WG exactly 64 ds_add_f32 per thread ->
// per-CU LDS-atomic load uniform, half of round-0's worst case.
// ---------------------------------------------------------------------------
__global__ __launch_bounds__(256) void gramscatter_kernel(
    const unsigned short* __restrict__ XThi, const unsigned short* __restrict__ XTlo,
    const int* __restrict__ h1, const float* __restrict__ s1,
    const int* __restrict__ h2, const float* __restrict__ s2,
    float* __restrict__ pbins)
{
    const int id  = blockIdx.x;             // 0..511
    const int sub = id >> 3;                // 0..63
    const int tp  = sub & 15;               // unit 0..15
    const int bat = (id & 7) + 8 * (sub >> 4);
    // units 0..3: diag tiles (t,t), fwd scatter
    // units 4..9: off-diag pairs (0,1)(0,2)(0,3)(1,2)(1,3)(2,3), fwd scatter
    // units 10..15: same pairs, mirror scatter
    const unsigned long long BI_PACK = 0x2110002110003210ULL;
    const unsigned long long BJ_PACK = 0x3323213323213210ULL;
    const int bi = (int)((BI_PACK >> (tp * 4)) & 15);
    const int bj = (int)((BJ_PACK >> (tp * 4)) & 15);
    const bool doFwd = (tp < 10);
    const bool doMir = (tp >= 10);

    const int tid  = threadIdx.x;
    const int w    = tid >> 6;
    const int lane = tid & 63;

    __shared__ __align__(16) unsigned short Sbuf[2][4][4096]; // 64 KB double buf
    __shared__ float bins[PROJ];                              // 32 KB
    __shared__ int   th1[256]; __shared__ float ts1[256];
    __shared__ int   th2[256]; __shared__ float ts2[256];

    const int tile = (w < 2) ? bi : bj;
    const unsigned short* srcbase = ((w & 1) ? XTlo : XThi)
                                  + (size_t)bat * NSLAB * 16384 + (size_t)tile * 4096;
    const int rowq = w >> 1, colq = w & 1;

    // issue async prefetch of slab 0 (16B per lane, lds dest wave-uniform base)
    {
        const unsigned short* src = srcbase;
        unsigned short* dst = &Sbuf[0][w][0];
#pragma unroll
        for (int i = 0; i < 8; ++i)
            __builtin_amdgcn_global_load_lds(
                (const __attribute__((address_space(1))) void*)(src + i * 512 + lane * 8),
                (__attribute__((address_space(3))) void*)(dst + i * 512), 16, 0, 0);
    }

    // overlap: zero bins + load h/s tables while slab 0 is in flight
    for (int i = tid; i < PROJ; i += 256) bins[i] = 0.f;
    {
        const int g = (tid < 128) ? (bi * 128 + tid) : (bj * 128 + tid - 128);
        th1[tid] = h1[g]; ts1[tid] = s1[g];
        th2[tid] = h2[g]; ts2[tid] = s2[g];
    }

    f32x4 acc[16];
#pragma unroll
    for (int i = 0; i < 16; ++i) { acc[i][0]=0.f; acc[i][1]=0.f; acc[i][2]=0.f; acc[i][3]=0.f; }

    for (int ks = 0; ks < NSLAB; ++ks) {
        __syncthreads();                 // drains vmcnt -> slab ks resident
        const int buf = ks & 1;

        if (ks + 1 < NSLAB) {            // prefetch next slab into other buffer
            const unsigned short* src = srcbase + (size_t)(ks + 1) * 16384;
            unsigned short* dst = &Sbuf[buf ^ 1][w][0];
#pragma unroll
            for (int i = 0; i < 8; ++i)
                __builtin_amdgcn_global_load_lds(
                    (const __attribute__((address_space(1))) void*)(src + i * 512 + lane * 8),
                    (__attribute__((address_space(3))) void*)(dst + i * 512), 16, 0, 0);
        }

        short8 ah[4], al[4], bh[4], bl[4];
#pragma unroll
        for (int t = 0; t < 4; ++t) {
            ah[t] = *(const short8*)&Sbuf[buf][0][(rowq * 4 + t) * 512 + lane * 8];
            al[t] = *(const short8*)&Sbuf[buf][1][(rowq * 4 + t) * 512 + lane * 8];
            bh[t] = *(const short8*)&Sbuf[buf][2][(colq * 4 + t) * 512 + lane * 8];
            bl[t] = *(const short8*)&Sbuf[buf][3][(colq * 4 + t) * 512 + lane * 8];
        }
#pragma unroll
        for (int mt = 0; mt < 4; ++mt)
#pragma unroll
            for (int nt = 0; nt < 4; ++nt) {
                const int idx = mt * 4 + nt;
                acc[idx] = __builtin_amdgcn_mfma_f32_16x16x32_bf16(ah[mt], bh[nt], acc[idx], 0, 0, 0);
                acc[idx] = __builtin_amdgcn_mfma_f32_16x16x32_bf16(ah[mt], bl[nt], acc[idx], 0, 0, 0);
                acc[idx] = __builtin_amdgcn_mfma_f32_16x16x32_bf16(al[mt], bh[nt], acc[idx], 0, 0, 0);
            }
    }

    // ---- scatter: C/D layout col=lane&15, row=(lane>>4)*4+reg ----
    int   h2c[4], h1c[4];
    float s2c[4], s1c[4];
#pragma unroll
    for (int nt = 0; nt < 4; ++nt) {
        const int cl = colq * 64 + nt * 16 + (lane & 15);
        h2c[nt] = th2[128 + cl]; s2c[nt] = ts2[128 + cl];
        h1c[nt] = th1[128 + cl]; s1c[nt] = ts1[128 + cl];
    }
    const int quad = lane >> 4;
#pragma unroll
    for (int mt = 0; mt < 4; ++mt)
#pragma unroll
        for (int reg = 0; reg < 4; ++reg) {
            const int rl = rowq * 64 + mt * 16 + quad * 4 + reg;
            const int   h1r = th1[rl]; const float s1r = ts1[rl];
            const int   h2r = th2[rl]; const float s2r = ts2[rl];
#pragma unroll
            for (int nt = 0; nt < 4; ++nt) {
                const float v = acc[mt * 4 + nt][reg];
                if (doFwd)
                    lds_fadd(&bins[(h1r + h2c[nt]) & (PROJ - 1)], s1r * s2c[nt] * v);
                if (doMir)
                    lds_fadd(&bins[(h1c[nt] + h2r) & (PROJ - 1)], s1c[nt] * s2r * v);
            }
        }
    __syncthreads();   // lgkmcnt(0) drain covers the ds_add_f32 ops

    float* dst = pbins + ((size_t)bat * NTP + tp) * PROJ;
    for (int i = tid * 4; i < PROJ; i += 1024)
        *(float4*)(dst + i) = *(const float4*)&bins[i];
}

// ---------------------------------------------------------------------------
// Kernel 4: reduce NTP partials per bin, signed sqrt, emit unnormalized y,
// accumulate per-batch sum |v| (== sum y^2). Grid (8, 32). (verbatim round-0)
// ---------------------------------------------------------------------------
__global__ __launch_bounds__(256) void reduce_kernel(
    const float* __restrict__ pbins, float* __restrict__ out,
    float* __restrict__ norm)
{
    const int chunk = blockIdx.x;
    const int bat   = blockIdx.y;
    const int tid   = threadIdx.x;
    const int base  = chunk * 1024 + tid * 4;

    const float* pb = pbins + (size_t)bat * NTP * PROJ;
    float4 v = make_float4(0.f, 0.f, 0.f, 0.f);
#pragma unroll
    for (int t = 0; t < NTP; ++t) {
        float4 p = *(const float4*)(pb + (size_t)t * PROJ + base);
        v.x += p.x; v.y += p.y; v.z += p.z; v.w += p.w;
    }

    float4 sv;
    sv.x = (v.x >= 0.f) ? sqrtf(v.x) : -sqrtf(-v.x);
    sv.y = (v.y >= 0.f) ? sqrtf(v.y) : -sqrtf(-v.y);
    sv.z = (v.z >= 0.f) ? sqrtf(v.z) : -sqrtf(-v.z);
    sv.w = (v.w >= 0.f) ? sqrtf(v.w) : -sqrtf(-v.w);
    *(float4*)(out + (size_t)bat * PROJ + base) = sv;

    float local = fabsf(v.x) + fabsf(v.y) + fabsf(v.z) + fabsf(v.w);
#pragma unroll
    for (int off = 32; off > 0; off >>= 1) local += __shfl_down(local, off, 64);

    __shared__ float wred[4];
    if ((tid & 63) == 0) wred[tid >> 6] = local;
    __syncthreads();
    if (tid == 0)
        unsafeAtomicAdd(&norm[bat], wred[0] + wred[1] + wred[2] + wred[3]);
}

// ---------------------------------------------------------------------------
// Kernel 5: scale by rsqrt(norm). Grid (8, 32). (verbatim round-0)
// ---------------------------------------------------------------------------
__global__ __launch_bounds__(256) void normalize_kernel(
    float* __restrict__ out, const float* __restrict__ norm)
{
    const int bat = blockIdx.y;
    const int idx = blockIdx.x * 1024 + threadIdx.x * 4;
    const float inv = rsqrtf(fmaxf(norm[bat], 1e-10f));
    float4* p = (float4*)(out + (size_t)bat * PROJ + idx);
    float4 v = *p;
    v.x *= inv; v.y *= inv; v.z *= inv; v.w *= inv;
    *p = v;
}

// ---------------------------------------------------------------------------
extern "C" void kernel_launch(void* const* d_in, const int* in_sizes, int n_in,
                              void* d_out, int out_size, void* d_ws, size_t ws_size,
                              hipStream_t stream)
{
    const float* x  = (const float*)d_in[0];   // [32,14,14,512]
    const float* M1 = (const float*)d_in[1];   // [512,8192]
    const float* M2 = (const float*)d_in[2];   // [512,8192]
    float* out = (float*)d_out;                // [32,8192]

    char* ws = (char*)d_ws;
    int*            h1    = (int*)   (ws + 0);
    float*          s1    = (float*) (ws + 2048);
    int*            h2    = (int*)   (ws + 4096);
    float*          s2    = (float*) (ws + 6144);
    float*          norm  = (float*) (ws + 8192);
    unsigned short* XThi  = (unsigned short*)(ws + 16384);      // 7,340,032 B
    unsigned short* XTlo  = (unsigned short*)(ws + 7356416);    // 7,340,032 B
    float*          pbins = (float*) (ws + 14696448);           // 16,777,216 B
    // total ws use ~31.5 MB

    extract_kernel<<<dim3(512, 2), 256, 0, stream>>>(M1, M2, h1, s1, h2, s2, norm);
    prep_kernel<<<dim3(NSLAB, NBATCH), 256, 0, stream>>>(x, XThi, XTlo);
    gramscatter_kernel<<<NTP * NBATCH, 256, 0, stream>>>(XThi, XTlo, h1, s1, h2, s2, pbins);
    reduce_kernel<<<dim3(8, NBATCH), 256, 0, stream>>>(pbins, out, norm);
    normalize_kernel<<<dim3(8, NBATCH), 256, 0, stream>>>(out, norm);
}

// Round 6
// 161.161 us; speedup vs baseline: 1.1500x; 1.0316x over previous
//
#include <hip/hip_runtime.h>
#include <math.h>

#define PROJ 8192
#define CDIM 512
#define HWPOS 196
#define NBATCH 32
#define NSLAB 7             // K padded 196 -> 224 = 7 slabs of 32
#define NUNITF 8            // fused units per batch: 2 diag-pairs + 6 off-diag (fwd+mir)
#define NPAGES 8            // pbins pages per batch

typedef __attribute__((ext_vector_type(8))) short   short8;
typedef __attribute__((ext_vector_type(4))) float   f32x4;

__device__ __forceinline__ unsigned short f2bf(float f) {
    unsigned u = __float_as_uint(f);
    u += 0x7fff + ((u >> 16) & 1);          // round-to-nearest-even
    return (unsigned short)(u >> 16);
}
__device__ __forceinline__ float bf2f(unsigned short h) {
    return __uint_as_float(((unsigned)h) << 16);
}

// Native no-return LDS fp32 atomic add. unsafeAtomicAdd/atomicAdd on a
// generic pointer into LDS takes the safe CAS path (~400 cyc/op); ds_add_f32
// is single-issue. lgkmcnt drained by __syncthreads().
__device__ __forceinline__ void lds_fadd(float* p, float v) {
    __attribute__((address_space(3))) float* lp =
        (__attribute__((address_space(3))) float*)p;
    asm volatile("ds_add_f32 %0, %1" : : "v"(lp), "v"(v) : "memory");
}

// ---------------------------------------------------------------------------
// Kernel 1: extract (h, s) from the dense sketch matrices + zero norm accum.
// (verbatim round-0)
// ---------------------------------------------------------------------------
__global__ __launch_bounds__(256) void extract_kernel(
    const float* __restrict__ M1, const float* __restrict__ M2,
    int* __restrict__ h1, float* __restrict__ s1,
    int* __restrict__ h2, float* __restrict__ s2,
    float* __restrict__ norm)
{
    const int row = blockIdx.x;
    const float* M = blockIdx.y ? M2 : M1;
    int*   h = blockIdx.y ? h2 : h1;
    float* s = blockIdx.y ? s2 : s1;
    const float* mrow = M + (size_t)row * PROJ;

    if (blockIdx.x == 0 && blockIdx.y == 0 && threadIdx.x < NBATCH)
        norm[threadIdx.x] = 0.0f;

    for (int i = threadIdx.x * 4; i < PROJ; i += 256 * 4) {
        float4 v = *(const float4*)(mrow + i);
        if (v.x != 0.0f) { h[row] = i + 0; s[row] = v.x; }
        if (v.y != 0.0f) { h[row] = i + 1; s[row] = v.y; }
        if (v.z != 0.0f) { h[row] = i + 2; s[row] = v.z; }
        if (v.w != 0.0f) { h[row] = i + 3; s[row] = v.w; }
    }
}

// ---------------------------------------------------------------------------
// Kernel 2: prep — split fp32 x into bf16 hi/lo, transpose to fragment order.
// Output layout (ushort): [b][kslab(7)][cgrp(32)][quad(4)][c16(16)][j(8)]
// i.e. element (c = cgrp*16+c16, k = kslab*32+quad*8+j); k>=196 zero-padded.
// (verbatim round-0)
// ---------------------------------------------------------------------------
__global__ __launch_bounds__(256) void prep_kernel(
    const float* __restrict__ x,
    unsigned short* __restrict__ XThi, unsigned short* __restrict__ XTlo)
{
    const int ks  = blockIdx.x;
    const int bat = blockIdx.y;
    const int tid = threadIdx.x;
    __shared__ float xt[32][513];            // +1 pad breaks bank conflicts

    const float* xb = x + (size_t)bat * HWPOS * CDIM;
    const int k0 = ks * 32;
#pragma unroll
    for (int i = 0; i < 16; ++i) {
        const int idx = i * 1024 + tid * 4;
        const int kr  = idx >> 9;
        const int c   = idx & 511;
        float4 v = make_float4(0.f, 0.f, 0.f, 0.f);
        if (k0 + kr < HWPOS) v = *(const float4*)(xb + (size_t)(k0 + kr) * CDIM + c);
        xt[kr][c+0] = v.x; xt[kr][c+1] = v.y; xt[kr][c+2] = v.z; xt[kr][c+3] = v.w;
    }
    __syncthreads();

    unsigned short* ohi = XThi + ((size_t)bat * NSLAB + ks) * 16384;
    unsigned short* olo = XTlo + ((size_t)bat * NSLAB + ks) * 16384;
#pragma unroll
    for (int i = 0; i < 8; ++i) {
        const int ch   = i * 256 + tid;      // chunk 0..2047, memory order
        const int c16  = ch & 15;
        const int quad = (ch >> 4) & 3;
        const int cgrp = ch >> 6;
        const int c    = cgrp * 16 + c16;
        short8 vh, vl;
#pragma unroll
        for (int j = 0; j < 8; ++j) {
            float f = xt[quad * 8 + j][c];
            unsigned short h = f2bf(f);
            vh[j] = (short)h;
            vl[j] = (short)f2bf(f - bf2f(h));
        }
        *(short8*)(ohi + ch * 8) = vh;
        *(short8*)(olo + ch * 8) = vl;
    }
}

// ---------------------------------------------------------------------------
// Kernel 3: fused Gram (bf16x2 MFMA) + count-sketch scatter.
// Round-4-verified double-buffered body, re-fused into 8 balanced units/batch:
//   unit 0: diag tiles (0,0)+(1,1)   (two sequential passes, fwd scatter)
//   unit 1: diag tiles (2,2)+(3,3)
//   units 2..7: off-diag pairs (0,1)(0,2)(0,3)(1,2)(1,3)(2,3) — ONE MFMA acc,
//               fwd + mirror scatter from it (round-0's verified dual lines).
// 256 WGs = ONE clean dispatch round at 1 WG/CU; every WG exactly 128
// ds_add_f32 per thread. vs r4: MFMA tiles 16->10/batch, flush+zero halved,
// one dispatch-round tail eliminated. Scatter work per CU is invariant.
// ---------------------------------------------------------------------------
__global__ __launch_bounds__(256) void gramscatter_kernel(
    const unsigned short* __restrict__ XThi, const unsigned short* __restrict__ XTlo,
    const int* __restrict__ h1, const float* __restrict__ s1,
    const int* __restrict__ h2, const float* __restrict__ s2,
    float* __restrict__ pbins)
{
    const int id  = blockIdx.x;             // 0..255
    const int sub = id >> 3;                // 0..31
    const int u   = sub & 7;                // fused unit 0..7
    const int bat = (id & 7) + 8 * (sub >> 3);
    const bool pair  = (u < 2);             // diag-pair unit (two passes)
    const bool doMir = (u >= 2);            // off-diag: fwd+mirror
    const int  k6    = u - 2;               // off-diag pair index 0..5

    const int tid  = threadIdx.x;
    const int w    = tid >> 6;
    const int lane = tid & 63;
    const int rowq = w >> 1, colq = w & 1;

    __shared__ __align__(16) unsigned short Sbuf[2][4][4096]; // 64 KB double buf
    __shared__ float bins[PROJ];                              // 32 KB
    __shared__ int   th1[256]; __shared__ float ts1[256];
    __shared__ int   th2[256]; __shared__ float ts2[256];

    for (int i = tid; i < PROJ; i += 256) bins[i] = 0.f;      // zero ONCE

    for (int rep = 0; rep < 2; ++rep) {
        if (rep == 1 && !pair) break;
        const int bi = pair ? (2 * u + rep) : (int)((0x211000u >> (k6 * 4)) & 15);
        const int bj = pair ? (2 * u + rep) : (int)((0x332321u >> (k6 * 4)) & 15);

        // tables for this rep (prev rep's scatter drained by its trailing sync)
        {
            const int g = (tid < 128) ? (bi * 128 + tid) : (bj * 128 + tid - 128);
            th1[tid] = h1[g]; ts1[tid] = s1[g];
            th2[tid] = h2[g]; ts2[tid] = s2[g];
        }

        const int tile = (w < 2) ? bi : bj;
        const unsigned short* srcbase = ((w & 1) ? XTlo : XThi)
                                      + (size_t)bat * NSLAB * 16384 + (size_t)tile * 4096;

        // issue async prefetch of slab 0 (r4-verbatim; drained at first B1)
        {
            const unsigned short* src = srcbase;
            unsigned short* dst = &Sbuf[0][w][0];
#pragma unroll
            for (int i = 0; i < 8; ++i)
                __builtin_amdgcn_global_load_lds(
                    (const __attribute__((address_space(1))) void*)(src + i * 512 + lane * 8),
                    (__attribute__((address_space(3))) void*)(dst + i * 512), 16, 0, 0);
        }

        f32x4 acc[16];
#pragma unroll
        for (int i = 0; i < 16; ++i) { acc[i][0]=0.f; acc[i][1]=0.f; acc[i][2]=0.f; acc[i][3]=0.f; }

        for (int ks = 0; ks < NSLAB; ++ks) {
            __syncthreads();                 // drains vmcnt -> slab ks resident
            const int buf = ks & 1;

            if (ks + 1 < NSLAB) {            // prefetch next slab into other buffer
                const unsigned short* src = srcbase + (size_t)(ks + 1) * 16384;
                unsigned short* dst = &Sbuf[buf ^ 1][w][0];
#pragma unroll
                for (int i = 0; i < 8; ++i)
                    __builtin_amdgcn_global_load_lds(
                        (const __attribute__((address_space(1))) void*)(src + i * 512 + lane * 8),
                        (__attribute__((address_space(3))) void*)(dst + i * 512), 16, 0, 0);
            }

            short8 ah[4], al[4], bh[4], bl[4];
#pragma unroll
            for (int t = 0; t < 4; ++t) {
                ah[t] = *(const short8*)&Sbuf[buf][0][(rowq * 4 + t) * 512 + lane * 8];
                al[t] = *(const short8*)&Sbuf[buf][1][(rowq * 4 + t) * 512 + lane * 8];
                bh[t] = *(const short8*)&Sbuf[buf][2][(colq * 4 + t) * 512 + lane * 8];
                bl[t] = *(const short8*)&Sbuf[buf][3][(colq * 4 + t) * 512 + lane * 8];
            }
#pragma unroll
            for (int mt = 0; mt < 4; ++mt)
#pragma unroll
                for (int nt = 0; nt < 4; ++nt) {
                    const int idx = mt * 4 + nt;
                    acc[idx] = __builtin_amdgcn_mfma_f32_16x16x32_bf16(ah[mt], bh[nt], acc[idx], 0, 0, 0);
                    acc[idx] = __builtin_amdgcn_mfma_f32_16x16x32_bf16(ah[mt], bl[nt], acc[idx], 0, 0, 0);
                    acc[idx] = __builtin_amdgcn_mfma_f32_16x16x32_bf16(al[mt], bh[nt], acc[idx], 0, 0, 0);
                }
        }

        // ---- scatter: C/D layout col=lane&15, row=(lane>>4)*4+reg ----
        int   h2c[4], h1c[4];
        float s2c[4], s1c[4];
#pragma unroll
        for (int nt = 0; nt < 4; ++nt) {
            const int cl = colq * 64 + nt * 16 + (lane & 15);
            h2c[nt] = th2[128 + cl]; s2c[nt] = ts2[128 + cl];
            h1c[nt] = th1[128 + cl]; s1c[nt] = ts1[128 + cl];
        }
        const int quad = lane >> 4;
#pragma unroll
        for (int mt = 0; mt < 4; ++mt)
#pragma unroll
            for (int reg = 0; reg < 4; ++reg) {
                const int rl = rowq * 64 + mt * 16 + quad * 4 + reg;
                const int   h1r = th1[rl]; const float s1r = ts1[rl];
                const int   h2r = th2[rl]; const float s2r = ts2[rl];
#pragma unroll
                for (int nt = 0; nt < 4; ++nt) {
                    const float v = acc[mt * 4 + nt][reg];
                    lds_fadd(&bins[(h1r + h2c[nt]) & (PROJ - 1)], s1r * s2c[nt] * v);
                    if (doMir)
                        lds_fadd(&bins[(h1c[nt] + h2r) & (PROJ - 1)], s1c[nt] * s2r * v);
                }
            }
        __syncthreads();   // lgkmcnt(0) drain covers the ds_add_f32 ops
    }

    float* dst = pbins + ((size_t)bat * NPAGES + u) * PROJ;
    for (int i = tid * 4; i < PROJ; i += 1024)
        *(float4*)(dst + i) = *(const float4*)&bins[i];
}

// ---------------------------------------------------------------------------
// Kernel 4: finalize — fuses reduce + normalize. One WG per batch (512 thr):
// sum 8 pages, signed sqrt into REGISTERS, block-reduce sum|bin| (= sum y^2),
// rsqrt, scale, store. No atomics, no second global pass, one fewer launch.
// ---------------------------------------------------------------------------
__global__ __launch_bounds__(512) void finalize_kernel(
    const float* __restrict__ pbins, float* __restrict__ out)
{
    const int bat = blockIdx.x;
    const int tid = threadIdx.x;
    const float* pb = pbins + (size_t)bat * NPAGES * PROJ;

    float4 y0, y1, y2, y3;      // 16 floats/thread = 8192/512*... (4 chunks x float4)
    float local = 0.f;

#pragma unroll
    for (int c = 0; c < 4; ++c) {
        const int base = c * 2048 + tid * 4;
        float4 a = make_float4(0.f, 0.f, 0.f, 0.f);
#pragma unroll
        for (int t = 0; t < NPAGES; ++t) {
            float4 p = *(const float4*)(pb + (size_t)t * PROJ + base);
            a.x += p.x; a.y += p.y; a.z += p.z; a.w += p.w;
        }
        local += fabsf(a.x) + fabsf(a.y) + fabsf(a.z) + fabsf(a.w);
        float4 sv;
        sv.x = (a.x >= 0.f) ? sqrtf(a.x) : -sqrtf(-a.x);
        sv.y = (a.y >= 0.f) ? sqrtf(a.y) : -sqrtf(-a.y);
        sv.z = (a.z >= 0.f) ? sqrtf(a.z) : -sqrtf(-a.z);
        sv.w = (a.w >= 0.f) ? sqrtf(a.w) : -sqrtf(-a.w);
        if (c == 0) y0 = sv; else if (c == 1) y1 = sv; else if (c == 2) y2 = sv; else y3 = sv;
    }

#pragma unroll
    for (int off = 32; off > 0; off >>= 1) local += __shfl_down(local, off, 64);

    __shared__ float wred[8];
    __shared__ float sinv;
    if ((tid & 63) == 0) wred[tid >> 6] = local;
    __syncthreads();
    if (tid == 0) {
        float t = 0.f;
#pragma unroll
        for (int i = 0; i < 8; ++i) t += wred[i];
        sinv = rsqrtf(fmaxf(t, 1e-10f));
    }
    __syncthreads();
    const float inv = sinv;

    float* ob = out + (size_t)bat * PROJ;
#pragma unroll
    for (int c = 0; c < 4; ++c) {
        float4 sv = (c == 0) ? y0 : (c == 1) ? y1 : (c == 2) ? y2 : y3;
        sv.x *= inv; sv.y *= inv; sv.z *= inv; sv.w *= inv;
        *(float4*)(ob + c * 2048 + tid * 4) = sv;
    }
}

// ---------------------------------------------------------------------------
extern "C" void kernel_launch(void* const* d_in, const int* in_sizes, int n_in,
                              void* d_out, int out_size, void* d_ws, size_t ws_size,
                              hipStream_t stream)
{
    const float* x  = (const float*)d_in[0];   // [32,14,14,512]
    const float* M1 = (const float*)d_in[1];   // [512,8192]
    const float* M2 = (const float*)d_in[2];   // [512,8192]
    float* out = (float*)d_out;                // [32,8192]

    char* ws = (char*)d_ws;
    int*            h1    = (int*)   (ws + 0);
    float*          s1    = (float*) (ws + 2048);
    int*            h2    = (int*)   (ws + 4096);
    float*          s2    = (float*) (ws + 6144);
    float*          norm  = (float*) (ws + 8192);
    unsigned short* XThi  = (unsigned short*)(ws + 16384);      // 7,340,032 B
    unsigned short* XTlo  = (unsigned short*)(ws + 7356416);    // 7,340,032 B
    float*          pbins = (float*) (ws + 14696448);           // 8,388,608 B
    // total ws use ~23.1 MB (< 25.2 MB proven in round 0)

    extract_kernel<<<dim3(512, 2), 256, 0, stream>>>(M1, M2, h1, s1, h2, s2, norm);
    prep_kernel<<<dim3(NSLAB, NBATCH), 256, 0, stream>>>(x, XThi, XTlo);
    gramscatter_kernel<<<NUNITF * NBATCH, 256, 0, stream>>>(XThi, XTlo, h1, s1, h2, s2, pbins);
    finalize_kernel<<<NBATCH, 512, 0, stream>>>(pbins, out);
}